// Round 4
// baseline (513.609 us; speedup 1.0000x reference)
//
#include <hip/hip_runtime.h>

// Problem constants (from reference config)
#define BATCH 4
#define NCAM  6
#define DNUM  41
#define FHN   8
#define FWN   22
#define CCH   128
#define NXV   200
#define NYV   200
#define NXY   40000      // NXV*NYV
#define NPTS  173184     // BATCH*NCAM*DNUM*FHN*FWN
#define TILE  64         // voxels per gather tile (divides NXY)
#define NTILES (BATCH * NXY / TILE)  // 2500

struct Mats {
    float iR[9];    // inv(post_rots), fp32 LU (gesv-style)
    float comb[9];  // rots @ inv(intrins), fp32 no-FMA matmul
    float tr[3];    // trans
    float pt[3];    // post_trans
};

// fp32 3x3 inverse mimicking numpy's linalg.inv -> LAPACK sgesv (see R1 notes).
__device__ void inv3x3_f32_gesv(const float* __restrict__ Ain, float* __restrict__ inv) {
#pragma clang fp contract(off)
    float A[9];
    for (int k = 0; k < 9; ++k) A[k] = Ain[k];
    int piv[3];
    for (int j = 0; j < 3; ++j) {
        int p = j;
        float amax = fabsf(A[j * 3 + j]);
        for (int i = j + 1; i < 3; ++i) {
            float v = fabsf(A[i * 3 + j]);
            if (v > amax) { amax = v; p = i; }
        }
        piv[j] = p;
        if (p != j)
            for (int k = 0; k < 3; ++k) { float t = A[j*3+k]; A[j*3+k] = A[p*3+k]; A[p*3+k] = t; }
        float rd = 1.0f / A[j * 3 + j];
        for (int i = j + 1; i < 3; ++i) A[i * 3 + j] = A[i * 3 + j] * rd;
        for (int i = j + 1; i < 3; ++i)
            for (int k = j + 1; k < 3; ++k)
                A[i * 3 + k] = A[i * 3 + k] - A[i * 3 + j] * A[j * 3 + k];
    }
    float rdiag[3] = {1.0f / A[0], 1.0f / A[4], 1.0f / A[8]};
    for (int c = 0; c < 3; ++c) {
        float b[3] = {0.0f, 0.0f, 0.0f};
        b[c] = 1.0f;
        for (int j = 0; j < 3; ++j) { int p = piv[j]; if (p != j) { float t = b[j]; b[j] = b[p]; b[p] = t; } }
        for (int k = 0; k < 3; ++k)
            for (int i = k + 1; i < 3; ++i)
                b[i] = b[i] - A[i * 3 + k] * b[k];
        for (int k = 2; k >= 0; --k) {
            b[k] = b[k] * rdiag[k];
            for (int i = 0; i < k; ++i)
                b[i] = b[i] - A[i * 3 + k] * b[k];
        }
        inv[0 + c] = b[0];
        inv[3 + c] = b[1];
        inv[6 + c] = b[2];
    }
}

__global__ void prep_kernel(const float* __restrict__ rots,
                            const float* __restrict__ trans,
                            const float* __restrict__ intrins,
                            const float* __restrict__ post_rots,
                            const float* __restrict__ post_trans,
                            Mats* __restrict__ mats) {
    int i = threadIdx.x;
    if (i >= BATCH * NCAM) return;
    Mats m;
    inv3x3_f32_gesv(post_rots + i * 9, m.iR);
    float invK[9];
    inv3x3_f32_gesv(intrins + i * 9, invK);
    {
#pragma clang fp contract(off)
        for (int r = 0; r < 3; ++r)
            for (int c = 0; c < 3; ++c) {
                float s = rots[i * 9 + r * 3 + 0] * invK[0 * 3 + c];
                s = s + rots[i * 9 + r * 3 + 1] * invK[1 * 3 + c];
                s = s + rots[i * 9 + r * 3 + 2] * invK[2 * 3 + c];
                m.comb[r * 3 + c] = s;
            }
    }
    for (int k = 0; k < 3; ++k) {
        m.tr[k] = trans[i * 3 + k];
        m.pt[k] = post_trans[i * 3 + k];
    }
    mats[i] = m;
}

// Geometry: voxel flat index (b*NXY + gx*NYV + gy) or -1 if dropped.
__device__ __forceinline__ int point_voxel(int p, const Mats* __restrict__ mats) {
#pragma clang fp contract(off)
    int w = p % FWN;
    int t = p / FWN;
    int h = t % FHN;
    t /= FHN;
    int d = t % DNUM;
    t /= DNUM;
    int n = t % NCAM;
    int b = t / NCAM;

    const Mats m = mats[b * NCAM + n];

    float u   = (float)((double)w * (351.0 / 21.0)); // linspace(0,351,22)
    float v   = (float)((double)h * (127.0 / 7.0));  // linspace(0,127,8)
    float dep = 4.0f + (float)d;                     // arange(4,45,1)

    float p0 = u - m.pt[0];
    float p1 = v - m.pt[1];
    float p2 = dep - m.pt[2];
    float q0 = m.iR[0] * p0; q0 = q0 + m.iR[1] * p1; q0 = q0 + m.iR[2] * p2;
    float q1 = m.iR[3] * p0; q1 = q1 + m.iR[4] * p1; q1 = q1 + m.iR[5] * p2;
    float q2 = m.iR[6] * p0; q2 = q2 + m.iR[7] * p1; q2 = q2 + m.iR[8] * p2;
    float r0 = q0 * q2;
    float r1 = q1 * q2;
    float e0 = m.comb[0] * r0; e0 = e0 + m.comb[1] * r1; e0 = e0 + m.comb[2] * q2; e0 = e0 + m.tr[0];
    float e1 = m.comb[3] * r0; e1 = e1 + m.comb[4] * r1; e1 = e1 + m.comb[5] * q2; e1 = e1 + m.tr[1];
    float e2 = m.comb[6] * r0; e2 = e2 + m.comb[7] * r1; e2 = e2 + m.comb[8] * q2; e2 = e2 + m.tr[2];

    float gxf = (e0 + 50.0f) / 0.5f;
    float gyf = (e1 + 50.0f) / 0.5f;
    float gzf = (e2 + 10.0f) / 20.0f;
    int gx = (int)gxf;
    int gy = (int)gyf;
    int gz = (int)gzf;
    if (gx < 0 || gx >= NXV || gy < 0 || gy >= NYV || gz < 0 || gz >= 1) return -1;
    return b * NXY + gx * NYV + gy;
}

// Pass A: per-point vid + per-tile histogram.
__global__ __launch_bounds__(256) void pass_vid_count(const Mats* __restrict__ mats,
                                                      int* __restrict__ vids,
                                                      int* __restrict__ counts) {
    int p = blockIdx.x * 256 + threadIdx.x;
    if (p >= NPTS) return;
    int vid = point_voxel(p, mats);
    vids[p] = vid;
    if (vid >= 0) atomicAdd(&counts[vid >> 6], 1);  // tile = vid/TILE
}

// Exclusive scan of counts[0..NTILES) -> offsets (NTILES+1) and cursor copy.
// One block, 256 threads, 10 elements/thread (2560 >= 2500).
__global__ __launch_bounds__(256) void scan_kernel(const int* __restrict__ counts,
                                                   int* __restrict__ offsets,
                                                   int* __restrict__ cursor) {
    __shared__ int csum[256];
    int t = threadIdx.x;
    int base = t * 10;
    int local[10];
    int s = 0;
    for (int i = 0; i < 10; ++i) {
        int idx = base + i;
        int v = (idx < NTILES) ? counts[idx] : 0;
        local[i] = v;
        s += v;
    }
    csum[t] = s;
    __syncthreads();
    // Kogge-Stone inclusive scan over 256 chunk sums
    for (int off = 1; off < 256; off <<= 1) {
        int v = (t >= off) ? csum[t - off] : 0;
        __syncthreads();
        csum[t] += v;
        __syncthreads();
    }
    int excl = (t > 0) ? csum[t - 1] : 0;
    for (int i = 0; i < 10; ++i) {
        int idx = base + i;
        if (idx < NTILES) { offsets[idx] = excl; cursor[idx] = excl; }
        excl += local[i];
    }
    if (t == 255) offsets[NTILES] = excl;
}

// Pass B: place point indices into per-tile segments.
__global__ __launch_bounds__(256) void pass_place(const int* __restrict__ vids,
                                                  int* __restrict__ cursor,
                                                  int* __restrict__ order) {
    int p = blockIdx.x * 256 + threadIdx.x;
    if (p >= NPTS) return;
    int vid = vids[p];
    if (vid < 0) return;
    int pos = atomicAdd(&cursor[vid >> 6], 1);
    order[pos] = p;
}

// Gather: one block per 64-voxel tile. Accumulate into LDS, write out
// directly in output layout (fully coalesced 256B runs). No global atomics,
// no separate zero-fill of out (empty voxels write zeros here).
__global__ __launch_bounds__(256) void gather_kernel(const float* __restrict__ feats,
                                                     const int* __restrict__ vids,
                                                     const int* __restrict__ offsets,
                                                     const int* __restrict__ order,
                                                     float* __restrict__ out) {
    __shared__ float acc[TILE][CCH + 1];  // +1 pad: conflict-free on both phases
    int tile = blockIdx.x;
    int tid = threadIdx.x;
    for (int i = tid; i < TILE * (CCH + 1); i += 256)
        ((float*)acc)[i] = 0.0f;
    __syncthreads();

    int start = offsets[tile];
    int end   = offsets[tile + 1];
    int vbase = tile * TILE;
    int j = tid >> 7;        // which of 2 points this half-block handles
    int c = tid & 127;       // channel
    for (int base = start; base < end; base += 2) {
        int ip = base + j;
        if (ip < end) {
            int p = order[ip];
            int v = vids[p] - vbase;
            float f = feats[(size_t)p * CCH + c];
            atomicAdd(&acc[v][c], f);   // ds_add_f32; two halves may share v
        }
    }
    __syncthreads();

    int b   = vbase / NXY;
    int xy0 = vbase % NXY;
    for (int i = tid; i < TILE * CCH; i += 256) {
        int cc = i >> 6;     // channel
        int v  = i & 63;     // voxel within tile
        out[((size_t)(b * CCH + cc)) * NXY + xy0 + v] = acc[v][cc];
    }
}

// Fallback (round-2 path) if workspace is too small.
__global__ __launch_bounds__(128) void scatter_direct_kernel(const float* __restrict__ feats,
                                                             const Mats* __restrict__ mats,
                                                             float* __restrict__ out) {
    int p = blockIdx.x;
    int vid = point_voxel(p, mats);
    if (vid < 0) return;
    int b  = vid / NXY;
    int xy = vid % NXY;
    int c = threadIdx.x;
    float f = feats[(size_t)p * CCH + c];
    atomicAdd(out + (size_t)(b * CCH + c) * NXY + xy, f);
}

extern "C" void kernel_launch(void* const* d_in, const int* in_sizes, int n_in,
                              void* d_out, int out_size, void* d_ws, size_t ws_size,
                              hipStream_t stream) {
    const float* cam_feats  = (const float*)d_in[0];
    const float* rots       = (const float*)d_in[1];
    const float* trans      = (const float*)d_in[2];
    const float* intrins    = (const float*)d_in[3];
    const float* post_rots  = (const float*)d_in[4];
    const float* post_trans = (const float*)d_in[5];
    float* out = (float*)d_out;

    // Workspace layout
    const size_t off_mats    = 0;
    const size_t off_vids    = 4096;
    const size_t off_counts  = off_vids + (size_t)NPTS * 4;
    const size_t off_offsets = off_counts + (size_t)NTILES * 4;
    const size_t off_cursor  = off_offsets + (size_t)(NTILES + 1) * 4;
    const size_t off_order   = off_cursor + (size_t)NTILES * 4;
    const size_t ws_need     = off_order + (size_t)NPTS * 4;

    Mats* mats = (Mats*)((char*)d_ws + off_mats);
    prep_kernel<<<1, 64, 0, stream>>>(rots, trans, intrins, post_rots, post_trans, mats);

    if (ws_size >= ws_need) {
        int* vids    = (int*)((char*)d_ws + off_vids);
        int* counts  = (int*)((char*)d_ws + off_counts);
        int* offsets = (int*)((char*)d_ws + off_offsets);
        int* cursor  = (int*)((char*)d_ws + off_cursor);
        int* order   = (int*)((char*)d_ws + off_order);

        hipMemsetAsync(counts, 0, (size_t)NTILES * 4, stream);
        int pblocks = (NPTS + 255) / 256;
        pass_vid_count<<<pblocks, 256, 0, stream>>>(mats, vids, counts);
        scan_kernel<<<1, 256, 0, stream>>>(counts, offsets, cursor);
        pass_place<<<pblocks, 256, 0, stream>>>(vids, cursor, order);
        gather_kernel<<<NTILES, 256, 0, stream>>>(cam_feats, vids, offsets, order, out);
    } else {
        hipMemsetAsync(d_out, 0, (size_t)out_size * sizeof(float), stream);
        scatter_direct_kernel<<<NPTS, CCH, 0, stream>>>(cam_feats, mats, out);
    }
}

// Round 5
// 353.469 us; speedup vs baseline: 1.4531x; 1.4531x over previous
//
#include <hip/hip_runtime.h>

// Problem constants (from reference config)
#define BATCH 4
#define NCAM  6
#define DNUM  41
#define FHN   8
#define FWN   22
#define CCH   128
#define NXV   200
#define NYV   200
#define NXY   40000      // NXV*NYV
#define NPTS  173184     // BATCH*NCAM*DNUM*FHN*FWN
#define TILE  8          // voxels per gather tile (divides NXY)
#define NTILES (BATCH * NXY / TILE)  // 20000
#define PADC  (CCH + 4)  // LDS row pad

struct Mats {
    float iR[9];    // inv(post_rots), fp32 LU (gesv-style)
    float comb[9];  // rots @ inv(intrins), fp32 no-FMA matmul
    float tr[3];    // trans
    float pt[3];    // post_trans
};

// fp32 3x3 inverse mimicking numpy's linalg.inv -> LAPACK sgesv (see R1 notes).
__device__ void inv3x3_f32_gesv(const float* __restrict__ Ain, float* __restrict__ inv) {
#pragma clang fp contract(off)
    float A[9];
    for (int k = 0; k < 9; ++k) A[k] = Ain[k];
    int piv[3];
    for (int j = 0; j < 3; ++j) {
        int p = j;
        float amax = fabsf(A[j * 3 + j]);
        for (int i = j + 1; i < 3; ++i) {
            float v = fabsf(A[i * 3 + j]);
            if (v > amax) { amax = v; p = i; }
        }
        piv[j] = p;
        if (p != j)
            for (int k = 0; k < 3; ++k) { float t = A[j*3+k]; A[j*3+k] = A[p*3+k]; A[p*3+k] = t; }
        float rd = 1.0f / A[j * 3 + j];
        for (int i = j + 1; i < 3; ++i) A[i * 3 + j] = A[i * 3 + j] * rd;
        for (int i = j + 1; i < 3; ++i)
            for (int k = j + 1; k < 3; ++k)
                A[i * 3 + k] = A[i * 3 + k] - A[i * 3 + j] * A[j * 3 + k];
    }
    float rdiag[3] = {1.0f / A[0], 1.0f / A[4], 1.0f / A[8]};
    for (int c = 0; c < 3; ++c) {
        float b[3] = {0.0f, 0.0f, 0.0f};
        b[c] = 1.0f;
        for (int j = 0; j < 3; ++j) { int p = piv[j]; if (p != j) { float t = b[j]; b[j] = b[p]; b[p] = t; } }
        for (int k = 0; k < 3; ++k)
            for (int i = k + 1; i < 3; ++i)
                b[i] = b[i] - A[i * 3 + k] * b[k];
        for (int k = 2; k >= 0; --k) {
            b[k] = b[k] * rdiag[k];
            for (int i = 0; i < k; ++i)
                b[i] = b[i] - A[i * 3 + k] * b[k];
        }
        inv[0 + c] = b[0];
        inv[3 + c] = b[1];
        inv[6 + c] = b[2];
    }
}

__global__ void prep_kernel(const float* __restrict__ rots,
                            const float* __restrict__ trans,
                            const float* __restrict__ intrins,
                            const float* __restrict__ post_rots,
                            const float* __restrict__ post_trans,
                            Mats* __restrict__ mats) {
    int i = threadIdx.x;
    if (i >= BATCH * NCAM) return;
    Mats m;
    inv3x3_f32_gesv(post_rots + i * 9, m.iR);
    float invK[9];
    inv3x3_f32_gesv(intrins + i * 9, invK);
    {
#pragma clang fp contract(off)
        for (int r = 0; r < 3; ++r)
            for (int c = 0; c < 3; ++c) {
                float s = rots[i * 9 + r * 3 + 0] * invK[0 * 3 + c];
                s = s + rots[i * 9 + r * 3 + 1] * invK[1 * 3 + c];
                s = s + rots[i * 9 + r * 3 + 2] * invK[2 * 3 + c];
                m.comb[r * 3 + c] = s;
            }
    }
    for (int k = 0; k < 3; ++k) {
        m.tr[k] = trans[i * 3 + k];
        m.pt[k] = post_trans[i * 3 + k];
    }
    mats[i] = m;
}

// Geometry: voxel flat index (b*NXY + gx*NYV + gy) or -1 if dropped.
__device__ __forceinline__ int point_voxel(int p, const Mats* __restrict__ mats) {
#pragma clang fp contract(off)
    int w = p % FWN;
    int t = p / FWN;
    int h = t % FHN;
    t /= FHN;
    int d = t % DNUM;
    t /= DNUM;
    int n = t % NCAM;
    int b = t / NCAM;

    const Mats m = mats[b * NCAM + n];

    float u   = (float)((double)w * (351.0 / 21.0)); // linspace(0,351,22)
    float v   = (float)((double)h * (127.0 / 7.0));  // linspace(0,127,8)
    float dep = 4.0f + (float)d;                     // arange(4,45,1)

    float p0 = u - m.pt[0];
    float p1 = v - m.pt[1];
    float p2 = dep - m.pt[2];
    float q0 = m.iR[0] * p0; q0 = q0 + m.iR[1] * p1; q0 = q0 + m.iR[2] * p2;
    float q1 = m.iR[3] * p0; q1 = q1 + m.iR[4] * p1; q1 = q1 + m.iR[5] * p2;
    float q2 = m.iR[6] * p0; q2 = q2 + m.iR[7] * p1; q2 = q2 + m.iR[8] * p2;
    float r0 = q0 * q2;
    float r1 = q1 * q2;
    float e0 = m.comb[0] * r0; e0 = e0 + m.comb[1] * r1; e0 = e0 + m.comb[2] * q2; e0 = e0 + m.tr[0];
    float e1 = m.comb[3] * r0; e1 = e1 + m.comb[4] * r1; e1 = e1 + m.comb[5] * q2; e1 = e1 + m.tr[1];
    float e2 = m.comb[6] * r0; e2 = e2 + m.comb[7] * r1; e2 = e2 + m.comb[8] * q2; e2 = e2 + m.tr[2];

    float gxf = (e0 + 50.0f) / 0.5f;
    float gyf = (e1 + 50.0f) / 0.5f;
    float gzf = (e2 + 10.0f) / 20.0f;
    int gx = (int)gxf;
    int gy = (int)gyf;
    int gz = (int)gzf;
    if (gx < 0 || gx >= NXV || gy < 0 || gy >= NYV || gz < 0 || gz >= 1) return -1;
    return b * NXY + gx * NYV + gy;
}

// Pass A: per-point vid + per-tile histogram.
__global__ __launch_bounds__(256) void pass_vid_count(const Mats* __restrict__ mats,
                                                      int* __restrict__ vids,
                                                      int* __restrict__ counts) {
    int p = blockIdx.x * 256 + threadIdx.x;
    if (p >= NPTS) return;
    int vid = point_voxel(p, mats);
    vids[p] = vid;
    if (vid >= 0) atomicAdd(&counts[vid / TILE], 1);
}

// Exclusive scan of counts[0..NTILES) -> offsets (NTILES+1) and cursor copy.
// One block, 256 threads, 79 elements/thread (20224 >= 20000).
#define SCAN_PER 79
__global__ __launch_bounds__(256) void scan_kernel(const int* __restrict__ counts,
                                                   int* __restrict__ offsets,
                                                   int* __restrict__ cursor) {
    __shared__ int csum[256];
    int t = threadIdx.x;
    int base = t * SCAN_PER;
    int local[SCAN_PER];
    int s = 0;
    for (int i = 0; i < SCAN_PER; ++i) {
        int idx = base + i;
        int v = (idx < NTILES) ? counts[idx] : 0;
        local[i] = v;
        s += v;
    }
    csum[t] = s;
    __syncthreads();
    for (int off = 1; off < 256; off <<= 1) {
        int v = (t >= off) ? csum[t - off] : 0;
        __syncthreads();
        csum[t] += v;
        __syncthreads();
    }
    int excl = (t > 0) ? csum[t - 1] : 0;
    for (int i = 0; i < SCAN_PER; ++i) {
        int idx = base + i;
        if (idx < NTILES) { offsets[idx] = excl; cursor[idx] = excl; }
        excl += local[i];
    }
    if (t == 255) offsets[NTILES] = excl;
}

// Pass B: place point indices into per-tile segments.
__global__ __launch_bounds__(256) void pass_place(const int* __restrict__ vids,
                                                  int* __restrict__ cursor,
                                                  int* __restrict__ order) {
    int p = blockIdx.x * 256 + threadIdx.x;
    if (p >= NPTS) return;
    int vid = vids[p];
    if (vid < 0) return;
    int pos = atomicAdd(&cursor[vid / TILE], 1);
    order[pos] = p;
}

// Gather: one block per 8-voxel tile, 256 threads.
// 8 points in flight: 32-lane group per point, lane l handles channels
// 4l..4l+3 via one float4 load + 4 LDS ds_add_f32. Iterations independent.
// Output written directly in out layout (float4, coalesced); empty tiles
// write zeros -> no output memset, no transpose, no global fp32 atomics.
__global__ __launch_bounds__(256) void gather_kernel(const float* __restrict__ feats,
                                                     const int* __restrict__ vids,
                                                     const int* __restrict__ offsets,
                                                     const int* __restrict__ order,
                                                     float* __restrict__ out) {
    __shared__ float acc[TILE][PADC];
    int tile = blockIdx.x;
    int tid = threadIdx.x;
    for (int i = tid; i < TILE * PADC; i += 256)
        ((float*)acc)[i] = 0.0f;
    __syncthreads();

    int start = offsets[tile];
    int end   = offsets[tile + 1];
    int vbase = tile * TILE;
    int g = tid >> 5;   // point slot 0..7
    int l = tid & 31;   // lane in group: channels 4l..4l+3
    const float4* feats4 = (const float4*)feats;
    for (int ip = start + g; ip < end; ip += 8) {
        int p = order[ip];
        int v = vids[p] - vbase;
        float4 f = feats4[(size_t)p * 32 + l];
        atomicAdd(&acc[v][4 * l + 0], f.x);
        atomicAdd(&acc[v][4 * l + 1], f.y);
        atomicAdd(&acc[v][4 * l + 2], f.z);
        atomicAdd(&acc[v][4 * l + 3], f.w);
    }
    __syncthreads();

    int b   = vbase / NXY;
    int xy0 = vbase % NXY;
    // 256 float4 stores cover TILE*CCH = 1024 floats: thread t -> c = t>>1,
    // voxel quad vq = (t&1)*4. xy0 is a multiple of 8 -> 16B aligned.
    int c  = tid >> 1;
    int vq = (tid & 1) * 4;
    float4 o;
    o.x = acc[vq + 0][c];
    o.y = acc[vq + 1][c];
    o.z = acc[vq + 2][c];
    o.w = acc[vq + 3][c];
    *(float4*)(out + ((size_t)(b * CCH + c)) * NXY + xy0 + vq) = o;
}

// Fallback (round-2 path) if workspace is too small.
__global__ __launch_bounds__(128) void scatter_direct_kernel(const float* __restrict__ feats,
                                                             const Mats* __restrict__ mats,
                                                             float* __restrict__ out) {
    int p = blockIdx.x;
    int vid = point_voxel(p, mats);
    if (vid < 0) return;
    int b  = vid / NXY;
    int xy = vid % NXY;
    int c = threadIdx.x;
    float f = feats[(size_t)p * CCH + c];
    atomicAdd(out + (size_t)(b * CCH + c) * NXY + xy, f);
}

extern "C" void kernel_launch(void* const* d_in, const int* in_sizes, int n_in,
                              void* d_out, int out_size, void* d_ws, size_t ws_size,
                              hipStream_t stream) {
    const float* cam_feats  = (const float*)d_in[0];
    const float* rots       = (const float*)d_in[1];
    const float* trans      = (const float*)d_in[2];
    const float* intrins    = (const float*)d_in[3];
    const float* post_rots  = (const float*)d_in[4];
    const float* post_trans = (const float*)d_in[5];
    float* out = (float*)d_out;

    // Workspace layout
    const size_t off_mats    = 0;
    const size_t off_vids    = 4096;
    const size_t off_counts  = off_vids + (size_t)NPTS * 4;
    const size_t off_offsets = off_counts + (size_t)NTILES * 4;
    const size_t off_cursor  = off_offsets + (size_t)(NTILES + 1) * 4;
    const size_t off_order   = off_cursor + (size_t)NTILES * 4;
    const size_t ws_need     = off_order + (size_t)NPTS * 4;

    Mats* mats = (Mats*)((char*)d_ws + off_mats);
    prep_kernel<<<1, 64, 0, stream>>>(rots, trans, intrins, post_rots, post_trans, mats);

    if (ws_size >= ws_need) {
        int* vids    = (int*)((char*)d_ws + off_vids);
        int* counts  = (int*)((char*)d_ws + off_counts);
        int* offsets = (int*)((char*)d_ws + off_offsets);
        int* cursor  = (int*)((char*)d_ws + off_cursor);
        int* order   = (int*)((char*)d_ws + off_order);

        hipMemsetAsync(counts, 0, (size_t)NTILES * 4, stream);
        int pblocks = (NPTS + 255) / 256;
        pass_vid_count<<<pblocks, 256, 0, stream>>>(mats, vids, counts);
        scan_kernel<<<1, 256, 0, stream>>>(counts, offsets, cursor);
        pass_place<<<pblocks, 256, 0, stream>>>(vids, cursor, order);
        gather_kernel<<<NTILES, 256, 0, stream>>>(cam_feats, vids, offsets, order, out);
    } else {
        hipMemsetAsync(d_out, 0, (size_t)out_size * sizeof(float), stream);
        scatter_direct_kernel<<<NPTS, CCH, 0, stream>>>(cam_feats, mats, out);
    }
}